// Round 13
// baseline (234.303 us; speedup 1.0000x reference)
//
#include <hip/hip_runtime.h>

typedef _Float16 f16x8 __attribute__((ext_vector_type(8)));
typedef _Float16 f16x4 __attribute__((ext_vector_type(4)));
typedef _Float16 f16x2 __attribute__((ext_vector_type(2)));
typedef float f32x4 __attribute__((ext_vector_type(4)));

#define MFMA16(a, b, c) __builtin_amdgcn_mfma_f32_16x16x32_f16(a, b, c, 0, 0, 0)

#define NROW 65536           // 256*256 rows
#define SEGB 16777216ull     // 16MB workspace segment
#define LOG2E 1.4426950408889634f

// ---------------------------------------------------------------------------
// Kernel 1 (round-13: weights ONLY, 21 blocks).  LayerNorm moved INTO k_proj:
// the 16384-block LN pass (65536 rows x 12 serial shfl + 48MB traffic) is
// replaced by per-tile fused LN.  Slabs 0..3 = Wq,Wk,Wv,Wg ; 4 = WbT
// (zero-padded) ; 5 = WoutT.
// ---------------------------------------------------------------------------
__global__ __launch_bounds__(256) void k_wt(
    const float* __restrict__ Wb, const float* __restrict__ Wq,
    const float* __restrict__ Wk, const float* __restrict__ Wv,
    const float* __restrict__ Wg, const float* __restrict__ Wout,
    _Float16* __restrict__ WtAll)
{
  __shared__ _Float16 sw[32 * 136];
  int bid = blockIdx.x;
  if (bid < 20) {
    // weight transpose+convert: Wt_m[n][k] = W_m[k][n], f16
    int mat = bid >> 2, n0 = (bid & 3) * 32;
    const float* src = (mat == 0) ? Wq : (mat == 1) ? Wk : (mat == 2) ? Wv
                       : (mat == 3) ? Wg : Wout;
    _Float16* dst = WtAll + ((mat == 4) ? 5 : mat) * 16384;  // Wout -> slab 5
    for (int it = 0; it < 16; ++it) {
      int e = threadIdx.x + it * 256;   // 4096 elems
      int c = e >> 5, j = e & 31;
      sw[j * 136 + c] = (_Float16)src[c * 128 + n0 + j];
    }
    __syncthreads();
    for (int it = 0; it < 2; ++it) {
      int ch = threadIdx.x + it * 256;  // 512 chunks of 8
      int n = ch >> 4, k8 = (ch & 15) * 8;
      *(int4*)(dst + (n0 + n) * 128 + k8) = *(const int4*)&sw[n * 136 + k8];
    }
  } else {
    // slab 4: WbT[n][k] = Wb[k][n] for n<4, zero for n>=4 (B-operand pad)
    _Float16* dst = WtAll + 4 * 16384;
    for (int e = threadIdx.x; e < 16384; e += 256) {
      int n = e >> 7, k = e & 127;
      dst[e] = (n < 4) ? (_Float16)Wb[k * 4 + n] : (_Float16)0.f;
    }
  }
}

// ---------------------------------------------------------------------------
// Kernel 2: FUSED LayerNorm + projections.  out = LN(z) @ W for W in
// {Wq,Wk,Wv,Wg,Wb}; sigmoid fused for Wg; by==4 stores bias*log2e at the
// bias-sigma position (low byte = (k&15)<<4 | k>>4 -> k_attn float4 loads).
// LN: 2 threads/row (partner = adjacent lane, one shfl_xor(1)), E[x^2]-mu^2
// variance, normalized straight into sA (f16).  The 5 by-variants of an
// m-tile share an XCD (decode below), so the fp32 z-tile is HBM-read once
// and L2-served 4x.  zln buffer eliminated.
// ---------------------------------------------------------------------------
__global__ __launch_bounds__(256) void k_proj(
    const float* __restrict__ z, const float* __restrict__ gamma,
    const float* __restrict__ beta, const _Float16* __restrict__ WtAll,
    _Float16* __restrict__ Qb, _Float16* __restrict__ Kb,
    _Float16* __restrict__ Vb, _Float16* __restrict__ Gb,
    float* __restrict__ biasT)
{
  __shared__ _Float16 sA[128 * 136];
  __shared__ _Float16 sB[128 * 136];
  int e = blockIdx.x;                 // 0..2559
  int xcd = e & 7;
  int t = e >> 3;                     // 0..319
  int by = t % 5;                     // mat select (0..4)
  int g = t / 5;                      // 0..63
  int m0 = (g * 8 + xcd) * 128;
  const _Float16* Bt = WtAll + by * 16384;
  _Float16* outp = (by == 0) ? Qb : (by == 1) ? Kb : (by == 2) ? Vb : Gb;
  int tid = threadIdx.x;
  // stage B
  for (int it = 0; it < 8; ++it) {
    int ch = tid + it * 256;           // 2048 chunks of 8 halfs
    int r = ch >> 4, c8 = (ch & 15) * 8;
    *(int4*)&sB[r * 136 + c8] = *(const int4*)(Bt + r * 128 + c8);
  }
  // fused LN of the A-tile: row = tid>>1, half = tid&1 (64 cols each)
  {
    int row = tid >> 1, half = tid & 1;
    const float* zr = z + (size_t)(m0 + row) * 128 + half * 64;
    float4 v[16];
    float s = 0.f, s2 = 0.f;
    #pragma unroll
    for (int q = 0; q < 16; ++q) {
      v[q] = ((const float4*)zr)[q];
      s  += (v[q].x + v[q].y) + (v[q].z + v[q].w);
      s2 += (v[q].x * v[q].x + v[q].y * v[q].y)
          + (v[q].z * v[q].z + v[q].w * v[q].w);
    }
    s += __shfl_xor(s, 1);
    s2 += __shfl_xor(s2, 1);
    float mu = s * 0.0078125f;
    float rs = rsqrtf(fmaxf(s2 * 0.0078125f - mu * mu, 0.f) + 1e-5f);
    #pragma unroll
    for (int q = 0; q < 16; ++q) {
      float4 g4 = ((const float4*)gamma)[half * 16 + q];
      float4 b4 = ((const float4*)beta)[half * 16 + q];
      f16x4 o;
      o.x = (_Float16)((v[q].x - mu) * rs * g4.x + b4.x);
      o.y = (_Float16)((v[q].y - mu) * rs * g4.y + b4.y);
      o.z = (_Float16)((v[q].z - mu) * rs * g4.z + b4.z);
      o.w = (_Float16)((v[q].w - mu) * rs * g4.w + b4.w);
      *(f16x4*)&sA[row * 136 + half * 64 + q * 4] = o;
    }
  }
  __syncthreads();
  int lane = tid & 63, w = tid >> 6;
  int mw = (w >> 1) * 64, nw = (w & 1) * 64;
  int lr = lane & 15, lg = lane >> 4;
  int ntm = (by == 4) ? 1 : 4;        // bias blocks: only nt=0 column-tile
  f32x4 z4 = {0.f, 0.f, 0.f, 0.f};
  f32x4 acc[4][4];
  #pragma unroll
  for (int mt = 0; mt < 4; ++mt)
    #pragma unroll
    for (int nt = 0; nt < 4; ++nt) acc[mt][nt] = z4;
  #pragma unroll
  for (int k0 = 0; k0 < 128; k0 += 32) {
    f16x8 af[4], bf[4];
    #pragma unroll
    for (int mt = 0; mt < 4; ++mt)
      af[mt] = *(const f16x8*)&sA[(mw + mt * 16 + lr) * 136 + k0 + lg * 8];
    #pragma unroll
    for (int nt = 0; nt < 4; ++nt)
      if (nt < ntm)
        bf[nt] = *(const f16x8*)&sB[(nw + nt * 16 + lr) * 136 + k0 + lg * 8];
    #pragma unroll
    for (int mt = 0; mt < 4; ++mt)
      #pragma unroll
      for (int nt = 0; nt < 4; ++nt)
        if (nt < ntm)
          acc[mt][nt] = MFMA16(af[mt], bf[nt], acc[mt][nt]);
  }
  if (by == 4) {
    // bias epilogue: value bias(j,k) -> biasT[h][ j*256 + bsig(k) ], *log2e
    if (nw == 0 && lr < 4) {
      #pragma unroll
      for (int mt = 0; mt < 4; ++mt)
        #pragma unroll
        for (int r = 0; r < 4; ++r) {
          int row = m0 + mw + mt * 16 + lg * 4 + r;
          int lowk = row & 255;
          int pos = (row & ~255) | ((lowk & 15) << 4) | (lowk >> 4);
          biasT[(size_t)lr * NROW + pos] = acc[mt][0][r] * LOG2E;
        }
    }
    return;
  }
  bool sig = (by == 3);
  #pragma unroll
  for (int mt = 0; mt < 4; ++mt)
    #pragma unroll
    for (int nt = 0; nt < 4; ++nt)
      #pragma unroll
      for (int r = 0; r < 4; ++r) {
        int row = m0 + mw + mt * 16 + lg * 4 + r;
        int col = nw + nt * 16 + lr;
        float v = acc[mt][nt][r];
        if (sig) v = 1.0f / (1.0f + __expf(-v));
        outp[(size_t)row * 128 + col] = (_Float16)v;
      }
}

// ---------------------------------------------------------------------------
// Kernel 3: attention per (i,h) — REVERTED to the round-9 best (57.6us,
// VGPR 128, 64KB LDS, no spill).  Session ledger: residency = min(LDS-blk,
// floor(256/VGPR)-blk); VGPR 128 -> 2 blocks regardless of LDS (r10-r12
// disproved LDS-only levers: 48KB flat, 25KB raised VGPR to 156 -> 1 blk).
// This kernel is a hard local optimum; 7 structural attempts, 0 wins.
// sigma(k) = (k&15)*16+(k>>4) on sP/sV/bias -> b128 P-stores, float4 bias.
// ---------------------------------------------------------------------------
__global__ __launch_bounds__(256) void k_attn(
    const _Float16* __restrict__ Qb, const _Float16* __restrict__ Kb,
    const _Float16* __restrict__ Vb, const _Float16* __restrict__ Gb,
    const float* __restrict__ biasT, _Float16* __restrict__ OG)
{
  __shared__ _Float16 sK[256 * 32];   // [k][d], chunk-swizzled
  __shared__ _Float16 sV[32 * 256];   // Vt [d][sigma(k)], chunk-swizzled
  __shared__ _Float16 sP[64 * 256];   // P  [j][sigma(k)], chunk-swizzled
  int i = blockIdx.x, h = blockIdx.y;
  int tid = threadIdx.x;
  size_t base = ((size_t)i * 256) * 128 + h * 32;
  // stage K: row r, chunk cx -> phys cx ^ ((r>>1)&3)   (k NOT permuted here)
  for (int it = 0; it < 4; ++it) {
    int ch = tid + it * 256;          // 1024 chunks
    int r = ch >> 2, cx = ch & 3;
    int p = cx ^ ((r >> 1) & 3);
    *(int4*)&sK[r * 32 + p * 8] = *(const int4*)(Kb + base + (size_t)r * 128 + cx * 8);
  }
  // stage V transposed+sigma-permuted: Vt[d][sigma(k)], chunk ^ (d&7)
  for (int it = 0; it < 4; ++it) {
    int ch = tid + it * 256;
    int k = ch >> 2, d8 = (ch & 3) * 8;
    f16x8 tv = *(const f16x8*)(Vb + base + (size_t)k * 128 + d8);
    int k2 = ((k & 15) << 4) | (k >> 4);
    int c2 = k2 >> 3, e2 = k2 & 7;
    #pragma unroll
    for (int jj = 0; jj < 8; ++jj) {
      int d = d8 + jj;
      int p = c2 ^ (d & 7);
      sV[d * 256 + p * 8 + e2] = tv[jj];
    }
  }
  __syncthreads();
  int lane = tid & 63, w = tid >> 6;
  int lr = lane & 15, lg = lane >> 4;
  const float scale = 0.2550348858f;  // log2(e)/sqrt(32)
  f32x4 z4 = {0.f, 0.f, 0.f, 0.f};
  for (int pass = 0; pass < 4; ++pass) {
    int jbase = pass * 64;
    // Q fragment straight from global (each row used once)
    int jq = jbase + w * 16 + lr;
    f16x8 aq = *(const f16x8*)(Qb + base + (size_t)jq * 128 + lg * 8);
    f32x4 sacc[16];
    __builtin_amdgcn_s_setprio(1);
    #pragma unroll
    for (int kt = 0; kt < 16; ++kt) {
      int r = kt * 16 + lr;
      int p = lg ^ ((r >> 1) & 3);
      f16x8 bk = *(const f16x8*)&sK[r * 32 + p * 8];
      sacc[kt] = MFMA16(aq, bk, z4);
    }
    __builtin_amdgcn_s_setprio(0);
    // softmax over k per row; bias is sigma-ordered -> 4 coalesced float4
    float rinv4[4];
    #pragma unroll
    for (int r = 0; r < 4; ++r) {
      int j = jbase + w * 16 + lg * 4 + r;
      const float* brow = biasT + (size_t)h * NROW + (size_t)j * 256 + lr * 16;
      float4 b4[4];
      #pragma unroll
      for (int m = 0; m < 4; ++m) b4[m] = ((const float4*)brow)[m];
      float mx = -1e30f;
      #pragma unroll
      for (int kt = 0; kt < 16; ++kt) {
        float bb = ((const float*)&b4[kt >> 2])[kt & 3];
        float sv = sacc[kt][r] * scale + bb;
        sacc[kt][r] = sv;
        mx = fmaxf(mx, sv);
      }
      #pragma unroll
      for (int msk = 1; msk < 16; msk <<= 1) mx = fmaxf(mx, __shfl_xor(mx, msk));
      float sum = 0.f;
      f16x8 h0, h1;
      #pragma unroll
      for (int kt = 0; kt < 16; ++kt) {
        float pv = exp2f(sacc[kt][r] - mx);
        sum += pv;
        if (kt < 8) h0[kt] = (_Float16)pv;
        else        h1[kt - 8] = (_Float16)pv;
      }
      #pragma unroll
      for (int msk = 1; msk < 16; msk <<= 1) sum += __shfl_xor(sum, msk);
      rinv4[r] = 1.0f / sum;
      // sigma(kt*16+lr) = lr*16+kt -> 16 contiguous halfs = chunks 2lr,2lr+1
      int row = w * 16 + lg * 4 + r;
      *(f16x8*)&sP[row * 256 + ((2 * lr) ^ (row & 7)) * 8] = h0;
      *(f16x8*)&sP[row * 256 + ((2 * lr + 1) ^ (row & 7)) * 8] = h1;
    }
    // O = P @ V  (sigma-consistent windows; wave reads only its own P rows)
    f32x4 oacc[2] = {z4, z4};
    int prow = w * 16 + lr;
    #pragma unroll
    for (int ks = 0; ks < 8; ++ks) {
      int c = ks * 4 + lg;
      f16x8 ap = *(const f16x8*)&sP[prow * 256 + (c ^ (prow & 7)) * 8];
      __builtin_amdgcn_s_setprio(1);
      #pragma unroll
      for (int nt = 0; nt < 2; ++nt) {
        int d = nt * 16 + lr;
        f16x8 bv = *(const f16x8*)&sV[d * 256 + (c ^ (d & 7)) * 8];
        oacc[nt] = MFMA16(ap, bv, oacc[nt]);
      }
      __builtin_amdgcn_s_setprio(0);
    }
    // gate with G (sigmoid already applied), deferred normalize, store
    #pragma unroll
    for (int nt = 0; nt < 2; ++nt)
      #pragma unroll
      for (int r = 0; r < 4; ++r) {
        int j = jbase + w * 16 + lg * 4 + r;
        int d = nt * 16 + lr;
        size_t idx = base + (size_t)j * 128 + d;
        float g = (float)Gb[idx];
        OG[idx] = (_Float16)(oacc[nt][r] * rinv4[r] * g);
      }
  }
}

// ---------------------------------------------------------------------------
// Kernel 4: out = OG @ Wout  (fp32 output)
// ---------------------------------------------------------------------------
__global__ __launch_bounds__(256) void k_outp(
    const _Float16* __restrict__ A, const _Float16* __restrict__ Bt,
    float* __restrict__ out)
{
  __shared__ _Float16 sA[128 * 136];
  __shared__ _Float16 sB[128 * 136];
  int m0 = blockIdx.x * 128;
  int tid = threadIdx.x;
  for (int it = 0; it < 8; ++it) {
    int ch = tid + it * 256;
    int r = ch >> 4, c8 = (ch & 15) * 8;
    *(int4*)&sA[r * 136 + c8] = *(const int4*)(A + (size_t)(m0 + r) * 128 + c8);
    *(int4*)&sB[r * 136 + c8] = *(const int4*)(Bt + r * 128 + c8);
  }
  __syncthreads();
  int lane = tid & 63, w = tid >> 6;
  int mw = (w >> 1) * 64, nw = (w & 1) * 64;
  int lr = lane & 15, lg = lane >> 4;
  f32x4 z4 = {0.f, 0.f, 0.f, 0.f};
  f32x4 acc[4][4];
  #pragma unroll
  for (int mt = 0; mt < 4; ++mt)
    #pragma unroll
    for (int nt = 0; nt < 4; ++nt) acc[mt][nt] = z4;
  #pragma unroll
  for (int k0 = 0; k0 < 128; k0 += 32) {
    f16x8 af[4], bf[4];
    #pragma unroll
    for (int mt = 0; mt < 4; ++mt)
      af[mt] = *(const f16x8*)&sA[(mw + mt * 16 + lr) * 136 + k0 + lg * 8];
    #pragma unroll
    for (int nt = 0; nt < 4; ++nt)
      bf[nt] = *(const f16x8*)&sB[(nw + nt * 16 + lr) * 136 + k0 + lg * 8];
    #pragma unroll
    for (int mt = 0; mt < 4; ++mt)
      #pragma unroll
      for (int nt = 0; nt < 4; ++nt)
        acc[mt][nt] = MFMA16(af[mt], bf[nt], acc[mt][nt]);
  }
  #pragma unroll
  for (int mt = 0; mt < 4; ++mt)
    #pragma unroll
    for (int nt = 0; nt < 4; ++nt)
      #pragma unroll
      for (int r = 0; r < 4; ++r) {
        int row = m0 + mw + mt * 16 + lg * 4 + r;
        int col = nw + nt * 16 + lr;
        out[(size_t)row * 128 + col] = acc[mt][nt][r];
      }
}

// ---------------------------------------------------------------------------
extern "C" void kernel_launch(void* const* d_in, const int* in_sizes, int n_in,
                              void* d_out, int out_size, void* d_ws, size_t ws_size,
                              hipStream_t stream) {
  (void)in_sizes; (void)n_in; (void)out_size; (void)ws_size;
  const float* z    = (const float*)d_in[0];
  const float* gam  = (const float*)d_in[1];
  const float* bet  = (const float*)d_in[2];
  const float* Wq   = (const float*)d_in[3];
  const float* Wk   = (const float*)d_in[4];
  const float* Wv   = (const float*)d_in[5];
  const float* Wb   = (const float*)d_in[6];
  const float* Wg   = (const float*)d_in[7];
  const float* Wout = (const float*)d_in[8];

  char* ws = (char*)d_ws;
  _Float16* OG    = (_Float16*)(ws);                 // 16MB (zln eliminated)
  _Float16* Qb    = (_Float16*)(ws + SEGB);
  _Float16* Kb    = (_Float16*)(ws + SEGB * 2);
  _Float16* Vb    = (_Float16*)(ws + SEGB * 3);
  _Float16* Gb    = (_Float16*)(ws + SEGB * 4);
  float*    biasT = (float*)   (ws + SEGB * 5);      // 1MB [4][65536] sigma'd
  _Float16* WtAll = (_Float16*)(ws + SEGB * 5 + 1048576);  // 6*16384 f16

  k_wt<<<21, 256, 0, stream>>>(Wb, Wq, Wk, Wv, Wg, Wout, WtAll);
  k_proj<<<2560, 256, 0, stream>>>(z, gam, bet, WtAll, Qb, Kb, Vb, Gb, biasT);
  k_attn<<<dim3(256, 4), 256, 0, stream>>>(Qb, Kb, Vb, Gb, biasT, OG);
  k_outp<<<512, 256, 0, stream>>>(OG, WtAll + 5 * 16384, (float*)d_out);
}

// Round 14
// 203.569 us; speedup vs baseline: 1.1510x; 1.1510x over previous
//
#include <hip/hip_runtime.h>

typedef _Float16 f16x8 __attribute__((ext_vector_type(8)));
typedef _Float16 f16x2 __attribute__((ext_vector_type(2)));
typedef float f32x4 __attribute__((ext_vector_type(4)));

#define MFMA16(a, b, c) __builtin_amdgcn_mfma_f32_16x16x32_f16(a, b, c, 0, 0, 0)

#define NROW 65536           // 256*256 rows
#define SEGB 16777216ull     // 16MB workspace segment
#define LOG2E 1.4426950408889634f

// ---------------------------------------------------------------------------
// Kernel 1 (r9 known-good, restored): LayerNorm (fp32) -> z_ln f16.  Bias is
// a 5th GEMM variant in k_proj.  Blocks >= 16384 transpose+convert weights:
// slabs 0..3 = Wq,Wk,Wv,Wg ; 4 = WbT (zero-padded) ; 5 = WoutT.
// r13 lesson: fusing LN into k_proj held 64 regs of z live -> VGPR 140 ->
// 1 blk/CU -> 112us.  Separate LN pass is cheaper.
// ---------------------------------------------------------------------------
__global__ __launch_bounds__(256) void k_ln(
    const float* __restrict__ z, const float* __restrict__ gamma,
    const float* __restrict__ beta, const float* __restrict__ Wb,
    const float* __restrict__ Wq, const float* __restrict__ Wk,
    const float* __restrict__ Wv, const float* __restrict__ Wg,
    const float* __restrict__ Wout,
    _Float16* __restrict__ zln, float* __restrict__ biasT,
    _Float16* __restrict__ WtAll)
{
  __shared__ _Float16 sw[32 * 136];
  int bid = blockIdx.x;
  if (bid < 16384) {
    int lane = threadIdx.x & 63;
    int w = threadIdx.x >> 6;
    int row = bid * 4 + w;
    float2 v = ((const float2*)(z + (size_t)row * 128))[lane];
    float s = v.x + v.y;
    #pragma unroll
    for (int m = 1; m < 64; m <<= 1) s += __shfl_xor(s, m);
    float mu = s * 0.0078125f;
    float dx = v.x - mu, dy = v.y - mu;
    float q = dx * dx + dy * dy;
    #pragma unroll
    for (int m = 1; m < 64; m <<= 1) q += __shfl_xor(q, m);
    float rs = rsqrtf(q * 0.0078125f + 1e-5f);
    float2 g2 = ((const float2*)gamma)[lane];
    float2 b2 = ((const float2*)beta)[lane];
    float y0 = dx * rs * g2.x + b2.x;
    float y1 = dy * rs * g2.y + b2.y;
    f16x2 pr; pr.x = (_Float16)y0; pr.y = (_Float16)y1;
    *(f16x2*)(zln + (size_t)row * 128 + 2 * lane) = pr;
  } else if (bid < 16384 + 20) {
    // weight transpose+convert: Wt_m[n][k] = W_m[k][n], f16
    int t = bid - 16384;            // 0..19 : 5 mats x 4 slabs of 32 n
    int mat = t >> 2, n0 = (t & 3) * 32;
    const float* src = (mat == 0) ? Wq : (mat == 1) ? Wk : (mat == 2) ? Wv
                       : (mat == 3) ? Wg : Wout;
    _Float16* dst = WtAll + ((mat == 4) ? 5 : mat) * 16384;  // Wout -> slab 5
    for (int it = 0; it < 16; ++it) {
      int e = threadIdx.x + it * 256;   // 4096 elems
      int c = e >> 5, j = e & 31;
      sw[j * 136 + c] = (_Float16)src[c * 128 + n0 + j];
    }
    __syncthreads();
    for (int it = 0; it < 2; ++it) {
      int ch = threadIdx.x + it * 256;  // 512 chunks of 8
      int n = ch >> 4, k8 = (ch & 15) * 8;
      *(int4*)(dst + (n0 + n) * 128 + k8) = *(const int4*)&sw[n * 136 + k8];
    }
  } else {
    // slab 4: WbT[n][k] = Wb[k][n] for n<4, zero for n>=4 (B-operand pad)
    _Float16* dst = WtAll + 4 * 16384;
    for (int e = threadIdx.x; e < 16384; e += 256) {
      int n = e >> 7, k = e & 127;
      dst[e] = (n < 4) ? (_Float16)Wb[k * 4 + n] : (_Float16)0.f;
    }
  }
}

// ---------------------------------------------------------------------------
// Kernel 2 (r9 known-good, restored): projections  out = z_ln @ W  for W in
// {Wq,Wk,Wv,Wg,Wb}, sigmoid fused for Wg; by==4 computes bias = z_ln @ Wb,
// stores *log2e at the bias-sigma position (low byte = (k&15)<<4 | k>>4 ->
// k_attn float4 loads).  Grid 2560 1-D, XCD-aware decode.
// ---------------------------------------------------------------------------
__global__ __launch_bounds__(256) void k_proj(
    const _Float16* __restrict__ A, const _Float16* __restrict__ WtAll,
    _Float16* __restrict__ Qb, _Float16* __restrict__ Kb,
    _Float16* __restrict__ Vb, _Float16* __restrict__ Gb,
    float* __restrict__ biasT)
{
  __shared__ _Float16 sA[128 * 136];
  __shared__ _Float16 sB[128 * 136];
  int e = blockIdx.x;                 // 0..2559
  int xcd = e & 7;
  int t = e >> 3;                     // 0..319
  int by = t % 5;                     // mat select (0..4)
  int g = t / 5;                      // 0..63
  int m0 = (g * 8 + xcd) * 128;
  const _Float16* Bt = WtAll + by * 16384;
  _Float16* outp = (by == 0) ? Qb : (by == 1) ? Kb : (by == 2) ? Vb : Gb;
  int tid = threadIdx.x;
  for (int it = 0; it < 8; ++it) {
    int ch = tid + it * 256;           // 2048 chunks of 8 halfs
    int r = ch >> 4, c8 = (ch & 15) * 8;
    *(int4*)&sA[r * 136 + c8] = *(const int4*)(A + (size_t)(m0 + r) * 128 + c8);
    *(int4*)&sB[r * 136 + c8] = *(const int4*)(Bt + r * 128 + c8);
  }
  __syncthreads();
  int lane = tid & 63, w = tid >> 6;
  int mw = (w >> 1) * 64, nw = (w & 1) * 64;
  int lr = lane & 15, lg = lane >> 4;
  int ntm = (by == 4) ? 1 : 4;        // bias blocks: only nt=0 column-tile
  f32x4 z4 = {0.f, 0.f, 0.f, 0.f};
  f32x4 acc[4][4];
  #pragma unroll
  for (int mt = 0; mt < 4; ++mt)
    #pragma unroll
    for (int nt = 0; nt < 4; ++nt) acc[mt][nt] = z4;
  #pragma unroll
  for (int k0 = 0; k0 < 128; k0 += 32) {
    f16x8 af[4], bf[4];
    #pragma unroll
    for (int mt = 0; mt < 4; ++mt)
      af[mt] = *(const f16x8*)&sA[(mw + mt * 16 + lr) * 136 + k0 + lg * 8];
    #pragma unroll
    for (int nt = 0; nt < 4; ++nt)
      if (nt < ntm)
        bf[nt] = *(const f16x8*)&sB[(nw + nt * 16 + lr) * 136 + k0 + lg * 8];
    #pragma unroll
    for (int mt = 0; mt < 4; ++mt)
      #pragma unroll
      for (int nt = 0; nt < 4; ++nt)
        if (nt < ntm)
          acc[mt][nt] = MFMA16(af[mt], bf[nt], acc[mt][nt]);
  }
  if (by == 4) {
    // bias epilogue: value bias(j,k) -> biasT[h][ j*256 + bsig(k) ], *log2e
    if (nw == 0 && lr < 4) {
      #pragma unroll
      for (int mt = 0; mt < 4; ++mt)
        #pragma unroll
        for (int r = 0; r < 4; ++r) {
          int row = m0 + mw + mt * 16 + lg * 4 + r;
          int lowk = row & 255;
          int pos = (row & ~255) | ((lowk & 15) << 4) | (lowk >> 4);
          biasT[(size_t)lr * NROW + pos] = acc[mt][0][r] * LOG2E;
        }
    }
    return;
  }
  bool sig = (by == 3);
  #pragma unroll
  for (int mt = 0; mt < 4; ++mt)
    #pragma unroll
    for (int nt = 0; nt < 4; ++nt)
      #pragma unroll
      for (int r = 0; r < 4; ++r) {
        int row = m0 + mw + mt * 16 + lg * 4 + r;
        int col = nw + nt * 16 + lr;
        float v = acc[mt][nt][r];
        if (sig) v = 1.0f / (1.0f + __expf(-v));
        outp[(size_t)row * 128 + col] = (_Float16)v;
      }
}

// ---------------------------------------------------------------------------
// Kernel 3: attention per (i,h) — r9 best (57.6us, VGPR 128, 64KB LDS).
// Hard local optimum (7 structural attempts, 0 wins); residency = min(LDS,
// floor(256/VGPR)) blocks.  UNTOUCHED (control).
// ---------------------------------------------------------------------------
__global__ __launch_bounds__(256) void k_attn(
    const _Float16* __restrict__ Qb, const _Float16* __restrict__ Kb,
    const _Float16* __restrict__ Vb, const _Float16* __restrict__ Gb,
    const float* __restrict__ biasT, _Float16* __restrict__ OG)
{
  __shared__ _Float16 sK[256 * 32];   // [k][d], chunk-swizzled
  __shared__ _Float16 sV[32 * 256];   // Vt [d][sigma(k)], chunk-swizzled
  __shared__ _Float16 sP[64 * 256];   // P  [j][sigma(k)], chunk-swizzled
  int i = blockIdx.x, h = blockIdx.y;
  int tid = threadIdx.x;
  size_t base = ((size_t)i * 256) * 128 + h * 32;
  // stage K: row r, chunk cx -> phys cx ^ ((r>>1)&3)   (k NOT permuted here)
  for (int it = 0; it < 4; ++it) {
    int ch = tid + it * 256;          // 1024 chunks
    int r = ch >> 2, cx = ch & 3;
    int p = cx ^ ((r >> 1) & 3);
    *(int4*)&sK[r * 32 + p * 8] = *(const int4*)(Kb + base + (size_t)r * 128 + cx * 8);
  }
  // stage V transposed+sigma-permuted: Vt[d][sigma(k)], chunk ^ (d&7)
  for (int it = 0; it < 4; ++it) {
    int ch = tid + it * 256;
    int k = ch >> 2, d8 = (ch & 3) * 8;
    f16x8 tv = *(const f16x8*)(Vb + base + (size_t)k * 128 + d8);
    int k2 = ((k & 15) << 4) | (k >> 4);
    int c2 = k2 >> 3, e2 = k2 & 7;
    #pragma unroll
    for (int jj = 0; jj < 8; ++jj) {
      int d = d8 + jj;
      int p = c2 ^ (d & 7);
      sV[d * 256 + p * 8 + e2] = tv[jj];
    }
  }
  __syncthreads();
  int lane = tid & 63, w = tid >> 6;
  int lr = lane & 15, lg = lane >> 4;
  const float scale = 0.2550348858f;  // log2(e)/sqrt(32)
  f32x4 z4 = {0.f, 0.f, 0.f, 0.f};
  for (int pass = 0; pass < 4; ++pass) {
    int jbase = pass * 64;
    // Q fragment straight from global (each row used once)
    int jq = jbase + w * 16 + lr;
    f16x8 aq = *(const f16x8*)(Qb + base + (size_t)jq * 128 + lg * 8);
    f32x4 sacc[16];
    __builtin_amdgcn_s_setprio(1);
    #pragma unroll
    for (int kt = 0; kt < 16; ++kt) {
      int r = kt * 16 + lr;
      int p = lg ^ ((r >> 1) & 3);
      f16x8 bk = *(const f16x8*)&sK[r * 32 + p * 8];
      sacc[kt] = MFMA16(aq, bk, z4);
    }
    __builtin_amdgcn_s_setprio(0);
    // softmax over k per row; bias is sigma-ordered -> 4 coalesced float4
    float rinv4[4];
    #pragma unroll
    for (int r = 0; r < 4; ++r) {
      int j = jbase + w * 16 + lg * 4 + r;
      const float* brow = biasT + (size_t)h * NROW + (size_t)j * 256 + lr * 16;
      float4 b4[4];
      #pragma unroll
      for (int m = 0; m < 4; ++m) b4[m] = ((const float4*)brow)[m];
      float mx = -1e30f;
      #pragma unroll
      for (int kt = 0; kt < 16; ++kt) {
        float bb = ((const float*)&b4[kt >> 2])[kt & 3];
        float sv = sacc[kt][r] * scale + bb;
        sacc[kt][r] = sv;
        mx = fmaxf(mx, sv);
      }
      #pragma unroll
      for (int msk = 1; msk < 16; msk <<= 1) mx = fmaxf(mx, __shfl_xor(mx, msk));
      float sum = 0.f;
      f16x8 h0, h1;
      #pragma unroll
      for (int kt = 0; kt < 16; ++kt) {
        float pv = exp2f(sacc[kt][r] - mx);
        sum += pv;
        if (kt < 8) h0[kt] = (_Float16)pv;
        else        h1[kt - 8] = (_Float16)pv;
      }
      #pragma unroll
      for (int msk = 1; msk < 16; msk <<= 1) sum += __shfl_xor(sum, msk);
      rinv4[r] = 1.0f / sum;
      // sigma(kt*16+lr) = lr*16+kt -> 16 contiguous halfs = chunks 2lr,2lr+1
      int row = w * 16 + lg * 4 + r;
      *(f16x8*)&sP[row * 256 + ((2 * lr) ^ (row & 7)) * 8] = h0;
      *(f16x8*)&sP[row * 256 + ((2 * lr + 1) ^ (row & 7)) * 8] = h1;
    }
    // O = P @ V  (sigma-consistent windows; wave reads only its own P rows)
    f32x4 oacc[2] = {z4, z4};
    int prow = w * 16 + lr;
    #pragma unroll
    for (int ks = 0; ks < 8; ++ks) {
      int c = ks * 4 + lg;
      f16x8 ap = *(const f16x8*)&sP[prow * 256 + (c ^ (prow & 7)) * 8];
      __builtin_amdgcn_s_setprio(1);
      #pragma unroll
      for (int nt = 0; nt < 2; ++nt) {
        int d = nt * 16 + lr;
        f16x8 bv = *(const f16x8*)&sV[d * 256 + (c ^ (d & 7)) * 8];
        oacc[nt] = MFMA16(ap, bv, oacc[nt]);
      }
      __builtin_amdgcn_s_setprio(0);
    }
    // gate with G (sigmoid already applied), deferred normalize, store
    #pragma unroll
    for (int nt = 0; nt < 2; ++nt)
      #pragma unroll
      for (int r = 0; r < 4; ++r) {
        int j = jbase + w * 16 + lg * 4 + r;
        int d = nt * 16 + lr;
        size_t idx = base + (size_t)j * 128 + d;
        float g = (float)Gb[idx];
        OG[idx] = (_Float16)(oacc[nt][r] * rinv4[r] * g);
      }
  }
}

// ---------------------------------------------------------------------------
// Kernel 4 (round-14 experiment): out = OG @ Wout (fp32).  r13 decomposition
// put the old 512-block version at ~55-60us vs a ~10us traffic roofline —
// latency-bound (2 full-CU blocks, serial 64KB-stage/compute/64KB-write).
// New: 32x128 tiles, grid 2048, 4 waves of 16x64 (acc[4] = 16 VGPRs), only
// A staged in LDS (8.5KB); B = Wout slab (32KB, shared by ALL blocks) read
// directly from global -> L1/L2-resident.  Low VGPR + tiny LDS -> more
// resident blocks of quarter duration -> staging pipelines under compute.
// ---------------------------------------------------------------------------
__global__ __launch_bounds__(256) void k_outp(
    const _Float16* __restrict__ A, const _Float16* __restrict__ Bt,
    float* __restrict__ out)
{
  __shared__ _Float16 sA[32 * 136];
  int m0 = blockIdx.x * 32;
  int tid = threadIdx.x;
  #pragma unroll
  for (int it = 0; it < 2; ++it) {
    int ch = tid + it * 256;          // 512 chunks of 8 halfs
    int r = ch >> 4, c8 = (ch & 15) * 8;
    *(int4*)&sA[r * 136 + c8] = *(const int4*)(A + (size_t)(m0 + r) * 128 + c8);
  }
  __syncthreads();
  int lane = tid & 63, w = tid >> 6;
  int mw = (w >> 1) * 16, nw = (w & 1) * 64;
  int lr = lane & 15, lg = lane >> 4;
  f32x4 z4 = {0.f, 0.f, 0.f, 0.f};
  f32x4 acc[4] = {z4, z4, z4, z4};
  #pragma unroll
  for (int k0 = 0; k0 < 128; k0 += 32) {
    f16x8 af = *(const f16x8*)&sA[(mw + lr) * 136 + k0 + lg * 8];
    #pragma unroll
    for (int nt = 0; nt < 4; ++nt) {
      f16x8 bf = *(const f16x8*)(Bt + (size_t)(nw + nt * 16 + lr) * 128 + k0 + lg * 8);
      acc[nt] = MFMA16(af, bf, acc[nt]);
    }
  }
  #pragma unroll
  for (int nt = 0; nt < 4; ++nt)
    #pragma unroll
    for (int r = 0; r < 4; ++r) {
      int row = m0 + mw + lg * 4 + r;
      int col = nw + nt * 16 + lr;
      out[(size_t)row * 128 + col] = acc[nt][r];
    }
}

// ---------------------------------------------------------------------------
extern "C" void kernel_launch(void* const* d_in, const int* in_sizes, int n_in,
                              void* d_out, int out_size, void* d_ws, size_t ws_size,
                              hipStream_t stream) {
  (void)in_sizes; (void)n_in; (void)out_size; (void)ws_size;
  const float* z    = (const float*)d_in[0];
  const float* gam  = (const float*)d_in[1];
  const float* bet  = (const float*)d_in[2];
  const float* Wq   = (const float*)d_in[3];
  const float* Wk   = (const float*)d_in[4];
  const float* Wv   = (const float*)d_in[5];
  const float* Wb   = (const float*)d_in[6];
  const float* Wg   = (const float*)d_in[7];
  const float* Wout = (const float*)d_in[8];

  char* ws = (char*)d_ws;
  _Float16* zln   = (_Float16*)(ws);                 // 16MB, reused as OG
  _Float16* Qb    = (_Float16*)(ws + SEGB);
  _Float16* Kb    = (_Float16*)(ws + SEGB * 2);
  _Float16* Vb    = (_Float16*)(ws + SEGB * 3);
  _Float16* Gb    = (_Float16*)(ws + SEGB * 4);
  float*    biasT = (float*)   (ws + SEGB * 5);      // 1MB [4][65536] sigma'd
  _Float16* WtAll = (_Float16*)(ws + SEGB * 5 + 1048576);  // 6*16384 f16

  k_ln<<<16405, 256, 0, stream>>>(z, gam, bet, Wb, Wq, Wk, Wv, Wg, Wout,
                                  zln, biasT, WtAll);
  k_proj<<<2560, 256, 0, stream>>>(zln, WtAll, Qb, Kb, Vb, Gb, biasT);
  k_attn<<<dim3(256, 4), 256, 0, stream>>>(Qb, Kb, Vb, Gb, biasT, zln);
  k_outp<<<2048, 256, 0, stream>>>(zln, WtAll + 5 * 16384, (float*)d_out);
}

// Round 15
// 186.373 us; speedup vs baseline: 1.2572x; 1.0923x over previous
//
#include <hip/hip_runtime.h>

typedef _Float16 f16x8 __attribute__((ext_vector_type(8)));
typedef _Float16 f16x4 __attribute__((ext_vector_type(4)));
typedef _Float16 f16x2 __attribute__((ext_vector_type(2)));
typedef float f32x4 __attribute__((ext_vector_type(4)));

#define MFMA16(a, b, c) __builtin_amdgcn_mfma_f32_16x16x32_f16(a, b, c, 0, 0, 0)

#define NROW 65536           // 256*256 rows
#define SEGB 16777216ull     // 16MB workspace segment
#define LOG2E 1.4426950408889634f

// ---------------------------------------------------------------------------
// Kernel 1 (round-15): LayerNorm (fp32) -> z_ln f16, 8 LANES PER ROW.
// Old: wave-per-row, 12-deep serial shfl chain, 8B/lane.  New: 32 rows/block
// (grid 2048), per lane 16 floats via 4x float4 (8 lanes x 16B = 128B
// contiguous per row per q -> fully coalesced), 3+3 interleaved shfl rounds
// (masks 1/2/4 within the 8-lane group), var = E[x^2]-mu^2 (fp32-safe at
// unit scale; numerics proven in r13's fused LN).  Bias stays in k_proj.
// Blocks >= 2048: weight transpose slabs 0..3 = Wq,Wk,Wv,Wg ; 4 = WbT
// (zero-padded) ; 5 = WoutT.
// ---------------------------------------------------------------------------
__global__ __launch_bounds__(256) void k_ln(
    const float* __restrict__ z, const float* __restrict__ gamma,
    const float* __restrict__ beta, const float* __restrict__ Wb,
    const float* __restrict__ Wq, const float* __restrict__ Wk,
    const float* __restrict__ Wv, const float* __restrict__ Wg,
    const float* __restrict__ Wout,
    _Float16* __restrict__ zln, float* __restrict__ biasT,
    _Float16* __restrict__ WtAll)
{
  __shared__ _Float16 sw[32 * 136];
  int bid = blockIdx.x;
  if (bid < 2048) {
    int tid = threadIdx.x;
    int rb = tid >> 3, sub = tid & 7;   // 32 rows/block, 8 lanes/row
    int row = bid * 32 + rb;
    const float* zr = z + (size_t)row * 128;
    float4 v[4];
    float s = 0.f, s2 = 0.f;
    #pragma unroll
    for (int q = 0; q < 4; ++q) {
      v[q] = *(const float4*)(zr + q * 32 + sub * 4);
      s  += (v[q].x + v[q].y) + (v[q].z + v[q].w);
      s2 += (v[q].x * v[q].x + v[q].y * v[q].y)
          + (v[q].z * v[q].z + v[q].w * v[q].w);
    }
    s += __shfl_xor(s, 1);  s2 += __shfl_xor(s2, 1);
    s += __shfl_xor(s, 2);  s2 += __shfl_xor(s2, 2);
    s += __shfl_xor(s, 4);  s2 += __shfl_xor(s2, 4);
    float mu = s * 0.0078125f;
    float rs = rsqrtf(fmaxf(s2 * 0.0078125f - mu * mu, 0.f) + 1e-5f);
    _Float16* zo = zln + (size_t)row * 128;
    #pragma unroll
    for (int q = 0; q < 4; ++q) {
      float4 g4 = *(const float4*)(gamma + q * 32 + sub * 4);
      float4 b4 = *(const float4*)(beta + q * 32 + sub * 4);
      f16x4 o;
      o.x = (_Float16)((v[q].x - mu) * rs * g4.x + b4.x);
      o.y = (_Float16)((v[q].y - mu) * rs * g4.y + b4.y);
      o.z = (_Float16)((v[q].z - mu) * rs * g4.z + b4.z);
      o.w = (_Float16)((v[q].w - mu) * rs * g4.w + b4.w);
      *(f16x4*)(zo + q * 32 + sub * 4) = o;
    }
  } else if (bid < 2048 + 20) {
    // weight transpose+convert: Wt_m[n][k] = W_m[k][n], f16
    int t = bid - 2048;             // 0..19 : 5 mats x 4 slabs of 32 n
    int mat = t >> 2, n0 = (t & 3) * 32;
    const float* src = (mat == 0) ? Wq : (mat == 1) ? Wk : (mat == 2) ? Wv
                       : (mat == 3) ? Wg : Wout;
    _Float16* dst = WtAll + ((mat == 4) ? 5 : mat) * 16384;  // Wout -> slab 5
    for (int it = 0; it < 16; ++it) {
      int e = threadIdx.x + it * 256;   // 4096 elems
      int c = e >> 5, j = e & 31;
      sw[j * 136 + c] = (_Float16)src[c * 128 + n0 + j];
    }
    __syncthreads();
    for (int it = 0; it < 2; ++it) {
      int ch = threadIdx.x + it * 256;  // 512 chunks of 8
      int n = ch >> 4, k8 = (ch & 15) * 8;
      *(int4*)(dst + (n0 + n) * 128 + k8) = *(const int4*)&sw[n * 136 + k8];
    }
  } else {
    // slab 4: WbT[n][k] = Wb[k][n] for n<4, zero for n>=4 (B-operand pad)
    _Float16* dst = WtAll + 4 * 16384;
    for (int e = threadIdx.x; e < 16384; e += 256) {
      int n = e >> 7, k = e & 127;
      dst[e] = (n < 4) ? (_Float16)Wb[k * 4 + n] : (_Float16)0.f;
    }
  }
}

// ---------------------------------------------------------------------------
// Kernel 2 (r9 known-good): projections  out = z_ln @ W  for W in
// {Wq,Wk,Wv,Wg,Wb}, sigmoid fused for Wg; by==4 computes bias = z_ln @ Wb,
// stores *log2e at the bias-sigma position (low byte = (k&15)<<4 | k>>4 ->
// k_attn float4 loads).  Grid 2560 1-D, XCD-aware decode.
// ---------------------------------------------------------------------------
__global__ __launch_bounds__(256) void k_proj(
    const _Float16* __restrict__ A, const _Float16* __restrict__ WtAll,
    _Float16* __restrict__ Qb, _Float16* __restrict__ Kb,
    _Float16* __restrict__ Vb, _Float16* __restrict__ Gb,
    float* __restrict__ biasT)
{
  __shared__ _Float16 sA[128 * 136];
  __shared__ _Float16 sB[128 * 136];
  int e = blockIdx.x;                 // 0..2559
  int xcd = e & 7;
  int t = e >> 3;                     // 0..319
  int by = t % 5;                     // mat select (0..4)
  int g = t / 5;                      // 0..63
  int m0 = (g * 8 + xcd) * 128;
  const _Float16* Bt = WtAll + by * 16384;
  _Float16* outp = (by == 0) ? Qb : (by == 1) ? Kb : (by == 2) ? Vb : Gb;
  int tid = threadIdx.x;
  for (int it = 0; it < 8; ++it) {
    int ch = tid + it * 256;           // 2048 chunks of 8 halfs
    int r = ch >> 4, c8 = (ch & 15) * 8;
    *(int4*)&sA[r * 136 + c8] = *(const int4*)(A + (size_t)(m0 + r) * 128 + c8);
    *(int4*)&sB[r * 136 + c8] = *(const int4*)(Bt + r * 128 + c8);
  }
  __syncthreads();
  int lane = tid & 63, w = tid >> 6;
  int mw = (w >> 1) * 64, nw = (w & 1) * 64;
  int lr = lane & 15, lg = lane >> 4;
  int ntm = (by == 4) ? 1 : 4;        // bias blocks: only nt=0 column-tile
  f32x4 z4 = {0.f, 0.f, 0.f, 0.f};
  f32x4 acc[4][4];
  #pragma unroll
  for (int mt = 0; mt < 4; ++mt)
    #pragma unroll
    for (int nt = 0; nt < 4; ++nt) acc[mt][nt] = z4;
  #pragma unroll
  for (int k0 = 0; k0 < 128; k0 += 32) {
    f16x8 af[4], bf[4];
    #pragma unroll
    for (int mt = 0; mt < 4; ++mt)
      af[mt] = *(const f16x8*)&sA[(mw + mt * 16 + lr) * 136 + k0 + lg * 8];
    #pragma unroll
    for (int nt = 0; nt < 4; ++nt)
      if (nt < ntm)
        bf[nt] = *(const f16x8*)&sB[(nw + nt * 16 + lr) * 136 + k0 + lg * 8];
    #pragma unroll
    for (int mt = 0; mt < 4; ++mt)
      #pragma unroll
      for (int nt = 0; nt < 4; ++nt)
        if (nt < ntm)
          acc[mt][nt] = MFMA16(af[mt], bf[nt], acc[mt][nt]);
  }
  if (by == 4) {
    // bias epilogue: value bias(j,k) -> biasT[h][ j*256 + bsig(k) ], *log2e
    if (nw == 0 && lr < 4) {
      #pragma unroll
      for (int mt = 0; mt < 4; ++mt)
        #pragma unroll
        for (int r = 0; r < 4; ++r) {
          int row = m0 + mw + mt * 16 + lg * 4 + r;
          int lowk = row & 255;
          int pos = (row & ~255) | ((lowk & 15) << 4) | (lowk >> 4);
          biasT[(size_t)lr * NROW + pos] = acc[mt][0][r] * LOG2E;
        }
    }
    return;
  }
  bool sig = (by == 3);
  #pragma unroll
  for (int mt = 0; mt < 4; ++mt)
    #pragma unroll
    for (int nt = 0; nt < 4; ++nt)
      #pragma unroll
      for (int r = 0; r < 4; ++r) {
        int row = m0 + mw + mt * 16 + lg * 4 + r;
        int col = nw + nt * 16 + lr;
        float v = acc[mt][nt][r];
        if (sig) v = 1.0f / (1.0f + __expf(-v));
        outp[(size_t)row * 128 + col] = (_Float16)v;
      }
}

// ---------------------------------------------------------------------------
// Kernel 3: attention per (i,h) — r9 best (57.6us, VGPR 128, 64KB LDS).
// Hard local optimum (7 structural attempts, 0 wins); residency = min(LDS,
// floor(256/VGPR)) blocks.  UNTOUCHED (control).
// ---------------------------------------------------------------------------
__global__ __launch_bounds__(256) void k_attn(
    const _Float16* __restrict__ Qb, const _Float16* __restrict__ Kb,
    const _Float16* __restrict__ Vb, const _Float16* __restrict__ Gb,
    const float* __restrict__ biasT, _Float16* __restrict__ OG)
{
  __shared__ _Float16 sK[256 * 32];   // [k][d], chunk-swizzled
  __shared__ _Float16 sV[32 * 256];   // Vt [d][sigma(k)], chunk-swizzled
  __shared__ _Float16 sP[64 * 256];   // P  [j][sigma(k)], chunk-swizzled
  int i = blockIdx.x, h = blockIdx.y;
  int tid = threadIdx.x;
  size_t base = ((size_t)i * 256) * 128 + h * 32;
  // stage K: row r, chunk cx -> phys cx ^ ((r>>1)&3)   (k NOT permuted here)
  for (int it = 0; it < 4; ++it) {
    int ch = tid + it * 256;          // 1024 chunks
    int r = ch >> 2, cx = ch & 3;
    int p = cx ^ ((r >> 1) & 3);
    *(int4*)&sK[r * 32 + p * 8] = *(const int4*)(Kb + base + (size_t)r * 128 + cx * 8);
  }
  // stage V transposed+sigma-permuted: Vt[d][sigma(k)], chunk ^ (d&7)
  for (int it = 0; it < 4; ++it) {
    int ch = tid + it * 256;
    int k = ch >> 2, d8 = (ch & 3) * 8;
    f16x8 tv = *(const f16x8*)(Vb + base + (size_t)k * 128 + d8);
    int k2 = ((k & 15) << 4) | (k >> 4);
    int c2 = k2 >> 3, e2 = k2 & 7;
    #pragma unroll
    for (int jj = 0; jj < 8; ++jj) {
      int d = d8 + jj;
      int p = c2 ^ (d & 7);
      sV[d * 256 + p * 8 + e2] = tv[jj];
    }
  }
  __syncthreads();
  int lane = tid & 63, w = tid >> 6;
  int lr = lane & 15, lg = lane >> 4;
  const float scale = 0.2550348858f;  // log2(e)/sqrt(32)
  f32x4 z4 = {0.f, 0.f, 0.f, 0.f};
  for (int pass = 0; pass < 4; ++pass) {
    int jbase = pass * 64;
    // Q fragment straight from global (each row used once)
    int jq = jbase + w * 16 + lr;
    f16x8 aq = *(const f16x8*)(Qb + base + (size_t)jq * 128 + lg * 8);
    f32x4 sacc[16];
    __builtin_amdgcn_s_setprio(1);
    #pragma unroll
    for (int kt = 0; kt < 16; ++kt) {
      int r = kt * 16 + lr;
      int p = lg ^ ((r >> 1) & 3);
      f16x8 bk = *(const f16x8*)&sK[r * 32 + p * 8];
      sacc[kt] = MFMA16(aq, bk, z4);
    }
    __builtin_amdgcn_s_setprio(0);
    // softmax over k per row; bias is sigma-ordered -> 4 coalesced float4
    float rinv4[4];
    #pragma unroll
    for (int r = 0; r < 4; ++r) {
      int j = jbase + w * 16 + lg * 4 + r;
      const float* brow = biasT + (size_t)h * NROW + (size_t)j * 256 + lr * 16;
      float4 b4[4];
      #pragma unroll
      for (int m = 0; m < 4; ++m) b4[m] = ((const float4*)brow)[m];
      float mx = -1e30f;
      #pragma unroll
      for (int kt = 0; kt < 16; ++kt) {
        float bb = ((const float*)&b4[kt >> 2])[kt & 3];
        float sv = sacc[kt][r] * scale + bb;
        sacc[kt][r] = sv;
        mx = fmaxf(mx, sv);
      }
      #pragma unroll
      for (int msk = 1; msk < 16; msk <<= 1) mx = fmaxf(mx, __shfl_xor(mx, msk));
      float sum = 0.f;
      f16x8 h0, h1;
      #pragma unroll
      for (int kt = 0; kt < 16; ++kt) {
        float pv = exp2f(sacc[kt][r] - mx);
        sum += pv;
        if (kt < 8) h0[kt] = (_Float16)pv;
        else        h1[kt - 8] = (_Float16)pv;
      }
      #pragma unroll
      for (int msk = 1; msk < 16; msk <<= 1) sum += __shfl_xor(sum, msk);
      rinv4[r] = 1.0f / sum;
      // sigma(kt*16+lr) = lr*16+kt -> 16 contiguous halfs = chunks 2lr,2lr+1
      int row = w * 16 + lg * 4 + r;
      *(f16x8*)&sP[row * 256 + ((2 * lr) ^ (row & 7)) * 8] = h0;
      *(f16x8*)&sP[row * 256 + ((2 * lr + 1) ^ (row & 7)) * 8] = h1;
    }
    // O = P @ V  (sigma-consistent windows; wave reads only its own P rows)
    f32x4 oacc[2] = {z4, z4};
    int prow = w * 16 + lr;
    #pragma unroll
    for (int ks = 0; ks < 8; ++ks) {
      int c = ks * 4 + lg;
      f16x8 ap = *(const f16x8*)&sP[prow * 256 + (c ^ (prow & 7)) * 8];
      __builtin_amdgcn_s_setprio(1);
      #pragma unroll
      for (int nt = 0; nt < 2; ++nt) {
        int d = nt * 16 + lr;
        f16x8 bv = *(const f16x8*)&sV[d * 256 + (c ^ (d & 7)) * 8];
        oacc[nt] = MFMA16(ap, bv, oacc[nt]);
      }
      __builtin_amdgcn_s_setprio(0);
    }
    // gate with G (sigmoid already applied), deferred normalize, store
    #pragma unroll
    for (int nt = 0; nt < 2; ++nt)
      #pragma unroll
      for (int r = 0; r < 4; ++r) {
        int j = jbase + w * 16 + lg * 4 + r;
        int d = nt * 16 + lr;
        size_t idx = base + (size_t)j * 128 + d;
        float g = (float)Gb[idx];
        OG[idx] = (_Float16)(oacc[nt][r] * rinv4[r] * g);
      }
  }
}

// ---------------------------------------------------------------------------
// Kernel 4 (r9 known-good, restored): out = OG @ Wout (fp32).  r14's 32-row
// global-B variant regressed +11.7us (un-hidden L2 latency in the MFMA
// chain); the 128x128 LDS-staged version is the best measured.
// ---------------------------------------------------------------------------
__global__ __launch_bounds__(256) void k_outp(
    const _Float16* __restrict__ A, const _Float16* __restrict__ Bt,
    float* __restrict__ out)
{
  __shared__ _Float16 sA[128 * 136];
  __shared__ _Float16 sB[128 * 136];
  int m0 = blockIdx.x * 128;
  int tid = threadIdx.x;
  for (int it = 0; it < 8; ++it) {
    int ch = tid + it * 256;
    int r = ch >> 4, c8 = (ch & 15) * 8;
    *(int4*)&sA[r * 136 + c8] = *(const int4*)(A + (size_t)(m0 + r) * 128 + c8);
    *(int4*)&sB[r * 136 + c8] = *(const int4*)(Bt + r * 128 + c8);
  }
  __syncthreads();
  int lane = tid & 63, w = tid >> 6;
  int mw = (w >> 1) * 64, nw = (w & 1) * 64;
  int lr = lane & 15, lg = lane >> 4;
  f32x4 z4 = {0.f, 0.f, 0.f, 0.f};
  f32x4 acc[4][4];
  #pragma unroll
  for (int mt = 0; mt < 4; ++mt)
    #pragma unroll
    for (int nt = 0; nt < 4; ++nt) acc[mt][nt] = z4;
  #pragma unroll
  for (int k0 = 0; k0 < 128; k0 += 32) {
    f16x8 af[4], bf[4];
    #pragma unroll
    for (int mt = 0; mt < 4; ++mt)
      af[mt] = *(const f16x8*)&sA[(mw + mt * 16 + lr) * 136 + k0 + lg * 8];
    #pragma unroll
    for (int nt = 0; nt < 4; ++nt)
      bf[nt] = *(const f16x8*)&sB[(nw + nt * 16 + lr) * 136 + k0 + lg * 8];
    #pragma unroll
    for (int mt = 0; mt < 4; ++mt)
      #pragma unroll
      for (int nt = 0; nt < 4; ++nt)
        acc[mt][nt] = MFMA16(af[mt], bf[nt], acc[mt][nt]);
  }
  #pragma unroll
  for (int mt = 0; mt < 4; ++mt)
    #pragma unroll
    for (int nt = 0; nt < 4; ++nt)
      #pragma unroll
      for (int r = 0; r < 4; ++r) {
        int row = m0 + mw + mt * 16 + lg * 4 + r;
        int col = nw + nt * 16 + lr;
        out[(size_t)row * 128 + col] = acc[mt][nt][r];
      }
}

// ---------------------------------------------------------------------------
extern "C" void kernel_launch(void* const* d_in, const int* in_sizes, int n_in,
                              void* d_out, int out_size, void* d_ws, size_t ws_size,
                              hipStream_t stream) {
  (void)in_sizes; (void)n_in; (void)out_size; (void)ws_size;
  const float* z    = (const float*)d_in[0];
  const float* gam  = (const float*)d_in[1];
  const float* bet  = (const float*)d_in[2];
  const float* Wq   = (const float*)d_in[3];
  const float* Wk   = (const float*)d_in[4];
  const float* Wv   = (const float*)d_in[5];
  const float* Wb   = (const float*)d_in[6];
  const float* Wg   = (const float*)d_in[7];
  const float* Wout = (const float*)d_in[8];

  char* ws = (char*)d_ws;
  _Float16* zln   = (_Float16*)(ws);                 // 16MB, reused as OG
  _Float16* Qb    = (_Float16*)(ws + SEGB);
  _Float16* Kb    = (_Float16*)(ws + SEGB * 2);
  _Float16* Vb    = (_Float16*)(ws + SEGB * 3);
  _Float16* Gb    = (_Float16*)(ws + SEGB * 4);
  float*    biasT = (float*)   (ws + SEGB * 5);      // 1MB [4][65536] sigma'd
  _Float16* WtAll = (_Float16*)(ws + SEGB * 5 + 1048576);  // 6*16384 f16

  k_ln<<<2069, 256, 0, stream>>>(z, gam, bet, Wb, Wq, Wk, Wv, Wg, Wout,
                                 zln, biasT, WtAll);
  k_proj<<<2560, 256, 0, stream>>>(zln, WtAll, Qb, Kb, Vb, Gb, biasT);
  k_attn<<<dim3(256, 4), 256, 0, stream>>>(Qb, Kb, Vb, Gb, biasT, zln);
  k_outp<<<512, 256, 0, stream>>>(zln, WtAll + 5 * 16384, (float*)d_out);
}